// Round 4
// baseline (96.299 us; speedup 1.0000x reference)
//
#include <hip/hip_runtime.h>
#include <math.h>

#define BB 4096
#define HH 512
#define KK 32
#define PAIRS ((KK * (KK - 1)) / 2)   // 496

constexpr int TH  = 16;          // h-values per stage1 block
constexpr int NBB = 16;          // B-chunks
constexpr int BC  = BB / NBB;    // 256 rows per block
constexpr int SUB = 64;          // rows staged in LDS at a time
constexpr int RP  = TH + 1;      // padded reduce stride (17)

// ---------------------------------------------------------------------------
// Compile-time coefficient tables for the exact t-CDF series (A&S 26.7.3/4):
//   even nu: A = sqrt(x) * sum_{j=0}^{nu/2-1}  ce[j] * (1-x)^j,
//            ce[j] = prod_{i=1..j} (2i-1)/(2i)
//   odd  nu: A = 2/pi * ( theta + sqrt(x(1-x)) * sum_{j=0}^{(nu-3)/2} co[j]*(1-x)^j ),
//            co[j] = prod_{i=1..j} (2i)/(2i+1),  theta = asin(sqrt(x))
// nu <= 4094 -> at most 2047 terms.
// ---------------------------------------------------------------------------
struct TabE {
    float v[2048];
    constexpr TabE() : v{} {
        double c = 1.0; v[0] = 1.0f;
        for (int j = 1; j < 2048; ++j) { c *= (2.0*j - 1.0) / (2.0*j); v[j] = (float)c; }
    }
};
struct TabO {
    float v[2048];
    constexpr TabO() : v{} {
        double c = 1.0; v[0] = 1.0f;
        for (int j = 1; j < 2048; ++j) { c *= (2.0*j) / (2.0*j + 1.0); v[j] = (float)c; }
    }
};
__device__ constexpr TabE tab_e{};
__device__ constexpr TabO tab_o{};

// ---------------------------------------------------------------------------
// Stage 1: per-chunk partial sums, NO atomics, NO zero-init required.
//   part_m[c][k][h] = sum_{b in chunk c} hidden[b,h]*cluster[b,k]
//   part_s[c][k][h] = sum_{b in chunk c} hidden^2 * cluster^2
//   pcol[c][k]      = sum_{b in chunk c} cluster[b,k]
// ---------------------------------------------------------------------------
__global__ __launch_bounds__(256) void stage1_kernel(
    const float* __restrict__ hidden, const float* __restrict__ cluster,
    float* __restrict__ part_m, float* __restrict__ part_s,
    float* __restrict__ pcol, float* __restrict__ ctl)
{
    __shared__ float hid_s [SUB * TH];     // 1024 f
    __shared__ float hid2_s[SUB * TH];     // 1024 f
    __shared__ float clu_s [SUB * KK];     // 2048 f
    __shared__ float red   [8 * KK * RP];  // 4352 f
    __shared__ float cred  [8 * KK];       // 256 f

    const int t  = threadIdx.x;
    const int ty = t >> 5;         // 0..7
    const int tx = t & 31;         // k index
    const int h0 = blockIdx.x * TH;
    const int c  = blockIdx.y;
    const int bchunk = c * BC;

    if (blockIdx.x == 0 && c == 0 && t == 0) {
        ctl[0] = 0.0f;                     // accum
        ((unsigned*)ctl)[1] = 0u;          // counter
    }

    float acc_m[TH], acc_s[TH];
#pragma unroll
    for (int i = 0; i < TH; ++i) { acc_m[i] = 0.f; acc_s[i] = 0.f; }
    float csum = 0.f;

    const float4* hid4 = (const float4*)hidden;
    const float4* clu4 = (const float4*)cluster;

    for (int sub = 0; sub < BC; sub += SUB) {
        const int b0 = bchunk + sub;
        {   // hidden tile: 64 rows x 16 cols = 256 float4; squares at load
            int r = t >> 2, q = t & 3;
            float4 v = hid4[(size_t)(b0 + r) * (HH / 4) + (h0 >> 2) + q];
            ((float4*)hid_s)[t] = v;
            float4 v2; v2.x = v.x*v.x; v2.y = v.y*v.y; v2.z = v.z*v.z; v2.w = v.w*v.w;
            ((float4*)hid2_s)[t] = v2;
        }
#pragma unroll
        for (int e = 0; e < 2; ++e) {      // cluster tile: 512 float4
            int u = t + e * 256;
            int r = u >> 3, q = u & 7;
            ((float4*)clu_s)[u] = clu4[(size_t)(b0 + r) * (KK / 4) + q];
        }
        __syncthreads();

        const float4* h4 = (const float4*)hid_s;
        const float4* g4 = (const float4*)hid2_s;
#pragma unroll
        for (int s = 0; s < SUB / 8; ++s) {
            int r = s * 8 + ty;
            float cc = clu_s[r * KK + tx];
            float c2 = cc * cc;
            csum += cc;
            float4 a0 = h4[r*4+0], a1 = h4[r*4+1], a2 = h4[r*4+2], a3 = h4[r*4+3];
            float4 b0 = g4[r*4+0], b1 = g4[r*4+1], b2 = g4[r*4+2], b3 = g4[r*4+3];
            acc_m[0]  = fmaf(a0.x, cc, acc_m[0]);  acc_m[1]  = fmaf(a0.y, cc, acc_m[1]);
            acc_m[2]  = fmaf(a0.z, cc, acc_m[2]);  acc_m[3]  = fmaf(a0.w, cc, acc_m[3]);
            acc_m[4]  = fmaf(a1.x, cc, acc_m[4]);  acc_m[5]  = fmaf(a1.y, cc, acc_m[5]);
            acc_m[6]  = fmaf(a1.z, cc, acc_m[6]);  acc_m[7]  = fmaf(a1.w, cc, acc_m[7]);
            acc_m[8]  = fmaf(a2.x, cc, acc_m[8]);  acc_m[9]  = fmaf(a2.y, cc, acc_m[9]);
            acc_m[10] = fmaf(a2.z, cc, acc_m[10]); acc_m[11] = fmaf(a2.w, cc, acc_m[11]);
            acc_m[12] = fmaf(a3.x, cc, acc_m[12]); acc_m[13] = fmaf(a3.y, cc, acc_m[13]);
            acc_m[14] = fmaf(a3.z, cc, acc_m[14]); acc_m[15] = fmaf(a3.w, cc, acc_m[15]);
            acc_s[0]  = fmaf(b0.x, c2, acc_s[0]);  acc_s[1]  = fmaf(b0.y, c2, acc_s[1]);
            acc_s[2]  = fmaf(b0.z, c2, acc_s[2]);  acc_s[3]  = fmaf(b0.w, c2, acc_s[3]);
            acc_s[4]  = fmaf(b1.x, c2, acc_s[4]);  acc_s[5]  = fmaf(b1.y, c2, acc_s[5]);
            acc_s[6]  = fmaf(b1.z, c2, acc_s[6]);  acc_s[7]  = fmaf(b1.w, c2, acc_s[7]);
            acc_s[8]  = fmaf(b2.x, c2, acc_s[8]);  acc_s[9]  = fmaf(b2.y, c2, acc_s[9]);
            acc_s[10] = fmaf(b2.z, c2, acc_s[10]); acc_s[11] = fmaf(b2.w, c2, acc_s[11]);
            acc_s[12] = fmaf(b3.x, c2, acc_s[12]); acc_s[13] = fmaf(b3.y, c2, acc_s[13]);
            acc_s[14] = fmaf(b3.z, c2, acc_s[14]); acc_s[15] = fmaf(b3.w, c2, acc_s[15]);
        }
        __syncthreads();
    }

    cred[ty * KK + tx] = csum;
    __syncthreads();
    if (blockIdx.x == 0 && t < KK) {
        float v = 0.f;
#pragma unroll
        for (int g = 0; g < 8; ++g) v += cred[g * KK + t];
        pcol[c * KK + t] = v;
    }

#pragma unroll
    for (int hh = 0; hh < TH; ++hh)
        red[ty * (KK * RP) + tx * RP + hh] = acc_m[hh];
    __syncthreads();
    for (int u = t; u < KK * TH; u += 256) {
        int k = u >> 4, hh = u & 15;
        float v = 0.f;
#pragma unroll
        for (int g = 0; g < 8; ++g) v += red[g * (KK * RP) + k * RP + hh];
        part_m[((size_t)c * KK + k) * HH + h0 + hh] = v;
    }
    __syncthreads();
#pragma unroll
    for (int hh = 0; hh < TH; ++hh)
        red[ty * (KK * RP) + tx * RP + hh] = acc_s[hh];
    __syncthreads();
    for (int u = t; u < KK * TH; u += 256) {
        int k = u >> 4, hh = u & 15;
        float v = 0.f;
#pragma unroll
        for (int g = 0; g < 8; ++g) v += red[g * (KK * RP) + k * RP + hh];
        part_s[((size_t)c * KK + k) * HH + h0 + hh] = v;
    }
}

// ---------------------------------------------------------------------------
__device__ __forceinline__ float frcp(float x) {
#if __has_builtin(__builtin_amdgcn_rcpf)
    return __builtin_amdgcn_rcpf(x);
#else
    return 1.0f / x;
#endif
}
__device__ __forceinline__ float guardf(float t) {
    return (fabsf(t) < 1e-30f) ? 1e-30f : t;
}

// NR betacf fallback (only for non-integer d2 — never taken with this data)
__device__ float betacf_fast(float a, float b, float x)
{
    const float EPS = 1e-5f;
    float qab = a + b, qap = a + 1.0f, qam = a - 1.0f;
    float c = 1.0f;
    float d = frcp(guardf(1.0f - qab * x * frcp(qap)));
    float h = d;
    for (int m = 1; m <= 100; ++m) {
        float fm = (float)m, m2 = 2.0f * fm;
        float aa = fm * (b - fm) * x * frcp((qam + m2) * (a + m2));
        d = frcp(guardf(fmaf(aa, d, 1.0f)));
        c = guardf(fmaf(aa, frcp(c), 1.0f));
        h *= d * c;
        float aa2 = -(a + fm) * (qab + fm) * x * frcp((a + m2) * (qap + m2));
        d = frcp(guardf(fmaf(aa2, d, 1.0f)));
        c = guardf(fmaf(aa2, frcp(c), 1.0f));
        float del = d * c;
        h *= del;
        if (__all(fabsf(del - 1.0f) < EPS)) break;
    }
    return h;
}

// ---------------------------------------------------------------------------
// Stage 2: one block (4 waves) per pair. Waves 0-3 chunk-reduce partials and
// compute x for 128 h each; wave 0: top-d of x (betainc monotone in x) then
// d parallel EXACT t-CDF series evals, sum logs, last-block writeout.
// ---------------------------------------------------------------------------
__global__ __launch_bounds__(256) void stage2_kernel(
    const float* __restrict__ part_m, const float* __restrict__ part_s,
    const float* __restrict__ pcol, float* __restrict__ ctl,
    const int* __restrict__ dptr, float* __restrict__ out)
{
    __shared__ float xs[HH];

    const int t = threadIdx.x;
    const int w = t >> 6, lane = t & 63;
    const int p = blockIdx.x;

    int i = 0, rem = p;
    while (true) { int row = KK - 1 - i; if (rem < row) break; rem -= row; ++i; }
    const int j = i + 1 + rem;

    float ci = 0.f, cj = 0.f;
#pragma unroll
    for (int cc = 0; cc < NBB; ++cc) {
        ci += pcol[cc * KK + i];
        cj += pcol[cc * KK + j];
    }
    ci = roundf(ci); cj = roundf(cj);
    const float pc = ci + cj;
    float d2 = pc - 2.0f;
    if (d2 == 0.0f) d2 = 1e-5f;
    const float b = 0.5f * d2;

#pragma unroll
    for (int q = 0; q < 2; ++q) {
        int h = w * 128 + q * 64 + lane;
        float mi = 0.f, mj = 0.f, si = 0.f, sj = 0.f;
#pragma unroll
        for (int cc = 0; cc < NBB; ++cc) {
            size_t base = (size_t)cc * KK * HH;
            mi += part_m[base + (size_t)i * HH + h];
            mj += part_m[base + (size_t)j * HH + h];
            si += part_s[base + (size_t)i * HH + h];
            sj += part_s[base + (size_t)j * HH + h];
        }
        float wi = fmaf((float)(BB - 2) * mi, mi, si);
        float wj = fmaf((float)(BB - 2) * mj, mj, sj);
        float dm = 0.5f * (mi - mj);
        float between = dm * dm * pc;
        float denom = between + wi + wj;
        float x = between / denom;
        if (!(x >= 1e-37f)) x = 1e-37f;       // also catches NaN
        x = fminf(x, 1.0f - 1e-5f);
        xs[h] = x;
    }
    __syncthreads();
    if (w != 0) return;

    // ---- wave 0: top-d selection over 512 x values (8/lane) ----
    float lv[8];
#pragma unroll
    for (int q = 0; q < 8; ++q) lv[q] = xs[q * 64 + lane];

    const int d = *dptr;
    float myx = 0.004f;
    float lm = lv[0];
#pragma unroll
    for (int q = 1; q < 8; ++q) lm = fmaxf(lm, lv[q]);

    for (int r = 0; r < d; ++r) {
        float gm = lm;
#pragma unroll
        for (int off = 1; off < 64; off <<= 1)
            gm = fmaxf(gm, __shfl_xor(gm, off));
        unsigned long long msk = __ballot(lm == gm);
        int winner = __ffsll((unsigned long long)msk) - 1;
        if (lane == r) myx = gm;
        if (lane == winner) {
            bool done = false;
#pragma unroll
            for (int q = 0; q < 8; ++q)
                if (!done && lv[q] == gm) { lv[q] = -1.0f; done = true; }
            lm = lv[0];
#pragma unroll
            for (int q = 1; q < 8; ++q) lm = fmaxf(lm, lv[q]);
        }
    }

    // ---- d parallel betainc evals: exact finite series for integer dof ----
    float x  = myx;
    float u  = 1.0f - x;          // cos^2(theta)
    float sx = sqrtf(x);          // sin(theta)
    int nu = (int)(d2 + 0.5f);
    float L;
    if (nu >= 1 && nu <= 4094 && fabsf(d2 - (float)nu) < 1e-3f) {
        float u2 = u * u;
        if (nu & 1) {
            int terms = (nu - 1) >> 1;       // j = 0..terms-1
            float S = 0.f;
            if (terms > 0) {
                float S0 = 0.f, S1 = 0.f, p0 = 1.f, p1 = u;
                int jj = 0;
                for (; jj + 1 < terms; jj += 2) {
                    S0 = fmaf(tab_o.v[jj],     p0, S0);
                    S1 = fmaf(tab_o.v[jj + 1], p1, S1);
                    p0 *= u2; p1 *= u2;
                }
                if (jj < terms) S0 = fmaf(tab_o.v[jj], p0, S0);
                S = S0 + S1;
            }
            float theta = asinf(fminf(sx, 1.0f));
            float A = 0.636619772367581343f * (theta + sx * sqrtf(u) * S);
            L = logf(fminf(A, 1.0f));
        } else {
            int terms = nu >> 1;             // j = 0..terms-1
            float S0 = 0.f, S1 = 0.f, p0 = 1.f, p1 = u;
            int jj = 0;
            for (; jj + 1 < terms; jj += 2) {
                S0 = fmaf(tab_e.v[jj],     p0, S0);
                S1 = fmaf(tab_e.v[jj + 1], p1, S1);
                p0 *= u2; p1 *= u2;
            }
            if (jj < terms) S0 = fmaf(tab_e.v[jj], p0, S0);
            float A = sx * (S0 + S1);
            L = logf(fminf(A, 1.0f));
        }
    } else {
        // fallback: NR continued fraction (non-integer d2)
        const float a = 0.5f;
        const float lg = lgammaf(a + b) - lgammaf(b) - 0.57236494f;
        const float xsplit = (a + 1.0f) / (a + b + 2.0f);
        bool  brA = x < xsplit;
        float al  = brA ? a : b;
        float be  = brA ? b : a;
        float xx  = brA ? x : u;
        float cf  = betacf_fast(al, be, xx);
        float lbt = lg + 0.5f * logf(x) + b * logf(u);
        if (brA) {
            L = lbt + logf(2.0f * fmaxf(cf, 1e-30f));
        } else {
            float tt = expf(lbt) * cf / b;
            tt = fminf(tt, 0.99999988f);
            L = log1pf(-tt);
        }
    }

    float val = (lane < d) ? L : 0.0f;
#pragma unroll
    for (int off = 1; off < 64; off <<= 1) val += __shfl_xor(val, off);

    if (lane == 0) {
        atomicAdd(&ctl[0], -val);
        __threadfence();
        unsigned old = atomicAdd((unsigned*)ctl + 1, 1u);
        if (old == PAIRS - 1) {
            out[0] = atomicAdd(&ctl[0], 0.0f);   // atomic read of final sum
        }
    }
}

// ---------------------------------------------------------------------------
extern "C" void kernel_launch(void* const* d_in, const int* in_sizes, int n_in,
                              void* d_out, int out_size, void* d_ws, size_t ws_size,
                              hipStream_t stream)
{
    const float* hidden  = (const float*)d_in[0];
    const float* cluster = (const float*)d_in[1];
    const int*   dptr    = (const int*)d_in[2];

    float* part_m = (float*)d_ws;                    // [NBB][KK][HH]
    float* part_s = part_m + (size_t)NBB * KK * HH;  // [NBB][KK][HH]
    float* pcol   = part_s + (size_t)NBB * KK * HH;  // [NBB][KK]
    float* ctl    = pcol + NBB * KK;                 // accum, counter

    dim3 g1(HH / TH, NBB);
    stage1_kernel<<<g1, 256, 0, stream>>>(hidden, cluster,
                                          part_m, part_s, pcol, ctl);
    stage2_kernel<<<PAIRS, 256, 0, stream>>>(part_m, part_s, pcol, ctl,
                                             dptr, (float*)d_out);
}